// Round 3
// baseline (913.616 us; speedup 1.0000x reference)
//
#include <hip/hip_runtime.h>

#define N_NODES 50000
#define N_RELSR 20
#define R_TOT   41          // 2*N_RELSR + 1
#define N_EDGES 500000
#define EMB     16
#define NCLS    16
#define NB      40
#define E_TOT   (2 * N_EDGES + N_NODES)   // 1,050,000
#define NE_COL  (N_NODES * EMB)           // 800,000
#define NBLK_N  ((N_NODES + 255) / 256)   // 196

// decode enriched edge i -> (s, o, r)
__device__ __forceinline__ void edge_decode(int i, const int* __restrict__ src,
                                            const int* __restrict__ dst,
                                            const int* __restrict__ rel,
                                            int& s, int& o, int& r) {
    if (i < N_EDGES) {
        s = src[i]; o = dst[i]; r = rel[i];
    } else if (i < 2 * N_EDGES) {
        int j = i - N_EDGES;
        s = dst[j]; o = src[j]; r = rel[j] + N_RELSR;
    } else {
        int n = i - 2 * N_EDGES;
        s = n; o = n; r = 2 * N_RELSR;
    }
}

// ---- K1: segment counts -----------------------------------------------------
__global__ void k_count(const int* __restrict__ src, const int* __restrict__ dst,
                        const int* __restrict__ rel, int* __restrict__ cnt) {
    int i = blockIdx.x * blockDim.x + threadIdx.x;
    if (i >= E_TOT) return;
    int s, o, r;
    edge_decode(i, src, dst, rel, s, o, r);
    atomicAdd(&cnt[r * N_NODES + s], 1);
}

// ---- K2a: deg[s] = sum_r cnt[r,s]; per-block sums ---------------------------
__global__ void k_degA(const int* __restrict__ cnt, int* __restrict__ deg,
                       int* __restrict__ bsum) {
    __shared__ int red[256];
    int t = threadIdx.x;
    int s = blockIdx.x * 256 + t;
    int d = 0;
    if (s < N_NODES) {
#pragma unroll
        for (int r = 0; r < R_TOT; r++) d += cnt[r * N_NODES + s];
        deg[s] = d;
    }
    red[t] = d;
    __syncthreads();
    for (int st = 128; st > 0; st >>= 1) {
        if (t < st) red[t] += red[t + st];
        __syncthreads();
    }
    if (t == 0) bsum[blockIdx.x] = red[0];
}

// ---- K2b: exclusive scan of 196 block sums (single tiny block) --------------
__global__ void k_degB(int* __restrict__ bsum) {
    __shared__ int sh[256];
    int t = threadIdx.x;
    int v = (t < NBLK_N) ? bsum[t] : 0;
    sh[t] = v;
    __syncthreads();
    for (int d = 1; d < 256; d <<= 1) {
        int x = (t >= d) ? sh[t - d] : 0;
        __syncthreads();
        sh[t] += x;
        __syncthreads();
    }
    if (t < NBLK_N) bsum[t] = sh[t] - v;   // exclusive
}

// ---- K2c: block-local scan of deg + apply block offset -> off, cursor -------
__global__ void k_degC(const int* __restrict__ deg, const int* __restrict__ bsum,
                       int* __restrict__ off, int* __restrict__ cursor) {
    __shared__ int sh[256];
    int t = threadIdx.x;
    int s = blockIdx.x * 256 + t;
    int d = (s < N_NODES) ? deg[s] : 0;
    sh[t] = d;
    __syncthreads();
    for (int dd = 1; dd < 256; dd <<= 1) {
        int x = (t >= dd) ? sh[t - dd] : 0;
        __syncthreads();
        sh[t] += x;
        __syncthreads();
    }
    int excl = sh[t] - d + bsum[blockIdx.x];
    if (s < N_NODES) { off[s] = excl; cursor[s] = excl; }
    if (s == 0) off[N_NODES] = E_TOT;
}

// ---- K3: fill CSR records {(r<<16)|o, v} sorted by s ------------------------
__global__ void k_fill(const int* __restrict__ src, const int* __restrict__ dst,
                       const int* __restrict__ rel, const int* __restrict__ cnt,
                       int* __restrict__ cursor, int2* __restrict__ recs) {
    int i = blockIdx.x * blockDim.x + threadIdx.x;
    if (i >= E_TOT) return;
    int s, o, r;
    edge_decode(i, src, dst, rel, s, o, r);
    float v = 1.0f / (float)cnt[r * N_NODES + s];
    int pos = atomicAdd(&cursor[s], 1);
    recs[pos] = make_int2((r << 16) | o, __float_as_int(v));
}

// ---- K4: w1[r,n,e] = sum_b comps1[r,b] * bases1[b,n,e]  (float2) ------------
__global__ void k_w1(const float* __restrict__ comps1, const float* __restrict__ bases1,
                     float* __restrict__ w1) {
    __shared__ float c1[R_TOT * NB];
    for (int q = threadIdx.x; q < R_TOT * NB; q += blockDim.x) c1[q] = comps1[q];
    __syncthreads();
    int j = blockIdx.x * blockDim.x + threadIdx.x;     // over NE_COL/2
    if (j >= NE_COL / 2) return;
    const float2* b2 = (const float2*)bases1;
    float2 base[NB];
#pragma unroll
    for (int b = 0; b < NB; b++) base[b] = b2[(size_t)b * (NE_COL / 2) + j];
    float2* w1p = (float2*)w1;
    for (int r = 0; r < R_TOT; r++) {
        float ax = 0.f, ay = 0.f;
#pragma unroll
        for (int b = 0; b < NB; b++) {
            float cc = c1[r * NB + b];
            ax += cc * base[b].x;
            ay += cc * base[b].y;
        }
        float2 acc; acc.x = ax; acc.y = ay;
        w1p[(size_t)r * (NE_COL / 2) + j] = acc;
    }
}

// ---- K5: w2t[r,c,e] = sum_b comps2[r,b] * bases2[b,e,c]  (transposed) -------
__global__ void k_w2(const float* __restrict__ comps2, const float* __restrict__ bases2,
                     float* __restrict__ w2t) {
    int r = blockIdx.x;        // 41 blocks
    int t = threadIdx.x;       // 256 = NCLS*EMB, t = c*16+e
    int c = t >> 4, e = t & 15;
    float acc = 0.f;
#pragma unroll 8
    for (int b = 0; b < NB; b++) acc += comps2[r * NB + b] * bases2[b * (EMB * NCLS) + e * NCLS + c];
    w2t[r * (EMB * NCLS) + t] = acc;
}

// ---- K6: layer-1 gather: h[s,e] = relu(bias1[e] + sum_j v*w1[r,o,e]) --------
// 4-way unroll to keep 4 random w1 gathers in flight per lane.
__global__ void k_l1_gather(const int* __restrict__ off, const int2* __restrict__ recs,
                            const float* __restrict__ w1, const float* __restrict__ bias1,
                            float* __restrict__ h) {
    int t = blockIdx.x * blockDim.x + threadIdx.x;     // N_NODES*16 exact
    int s = t >> 4, e = t & 15;
    int beg = off[s], end = off[s + 1];
    float acc = 0.f;
    int j = beg;
    for (; j + 3 < end; j += 4) {
        int2 r0 = recs[j], r1 = recs[j + 1], r2 = recs[j + 2], r3 = recs[j + 3];
        float f0 = w1[(size_t)(r0.x >> 16) * NE_COL + (r0.x & 0xFFFF) * EMB + e];
        float f1 = w1[(size_t)(r1.x >> 16) * NE_COL + (r1.x & 0xFFFF) * EMB + e];
        float f2 = w1[(size_t)(r2.x >> 16) * NE_COL + (r2.x & 0xFFFF) * EMB + e];
        float f3 = w1[(size_t)(r3.x >> 16) * NE_COL + (r3.x & 0xFFFF) * EMB + e];
        acc += __int_as_float(r0.y) * f0 + __int_as_float(r1.y) * f1 +
               __int_as_float(r2.y) * f2 + __int_as_float(r3.y) * f3;
    }
    for (; j < end; j++) {
        int2 rc = recs[j];
        acc += __int_as_float(rc.y) *
               w1[(size_t)(rc.x >> 16) * NE_COL + (rc.x & 0xFFFF) * EMB + e];
    }
    h[t] = fmaxf(acc + bias1[e], 0.f);
}

// ---- K6-alt (fallback if ws too small for w1): on-the-fly basis contraction -
__global__ void k_l1_gather_fly(const int* __restrict__ off, const int2* __restrict__ recs,
                                const float* __restrict__ comps1,
                                const float* __restrict__ bases1,
                                const float* __restrict__ bias1, float* __restrict__ h) {
    __shared__ float c1[R_TOT * NB];
    for (int q = threadIdx.x; q < R_TOT * NB; q += blockDim.x) c1[q] = comps1[q];
    __syncthreads();
    int t = blockIdx.x * blockDim.x + threadIdx.x;
    int s = t >> 4, e = t & 15;
    int beg = off[s], end = off[s + 1];
    float acc = 0.f;
    for (int j = beg; j < end; j++) {
        int2 rec = recs[j];
        int o = rec.x & 0xFFFF, r = rec.x >> 16;
        float v = __int_as_float(rec.y);
        const float* cr = &c1[r * NB];
        float w = 0.f;
#pragma unroll 8
        for (int b = 0; b < NB; b++) w += cr[b] * bases1[(size_t)b * NE_COL + o * EMB + e];
        acc += v * w;
    }
    h[t] = fmaxf(acc + bias1[e], 0.f);
}

// ---- K7: layer-2 gather: out[s,c] = bias2[c] + sum_j v * (h[o,:]·w2[r,:,c]) -
// w2 in LDS transposed [r][c][e], c-stride 20 (16B-aligned, 2-way banks only),
// r-stride 324. 4x ds_read_b128 per edge instead of 16 scalar reads.
#define W2C 20
#define W2R (16 * W2C + 4)    // 324
__global__ void k_l2_gather(const int* __restrict__ off, const int2* __restrict__ recs,
                            const float* __restrict__ h, const float* __restrict__ w2t,
                            const float* __restrict__ bias2, float* __restrict__ out) {
    __shared__ __align__(16) float w2s[R_TOT * W2R];   // 53,136 B
    for (int q = threadIdx.x; q < R_TOT * (EMB * NCLS); q += blockDim.x) {
        int r = q >> 8;
        int x = q & 255;
        int c = x >> 4, e = x & 15;
        w2s[r * W2R + c * W2C + e] = w2t[q];
    }
    __syncthreads();
    int t = blockIdx.x * blockDim.x + threadIdx.x;
    if (t >= NE_COL) return;
    int s = t >> 4, c = t & 15;
    int beg = off[s], end = off[s + 1];
    float bc = bias2[c];
    int cbase = c * W2C;
    float acc = 0.f;
    int j = beg;
    for (; j + 1 < end; j += 2) {
        int2 ra = recs[j], rb = recs[j + 1];
        float ha = h[(ra.x & 0xFFFF) * EMB + c];
        float hb = h[(rb.x & 0xFFFF) * EMB + c];
        const float4* wa = (const float4*)&w2s[(ra.x >> 16) * W2R + cbase];
        const float4* wb = (const float4*)&w2s[(rb.x >> 16) * W2R + cbase];
        float4 a0 = wa[0], a1 = wa[1], a2 = wa[2], a3 = wa[3];
        float4 b0 = wb[0], b1 = wb[1], b2 = wb[2], b3 = wb[3];
        float pa, pb;
        pa  = __shfl(ha,  0, 16) * a0.x; pa += __shfl(ha,  1, 16) * a0.y;
        pa += __shfl(ha,  2, 16) * a0.z; pa += __shfl(ha,  3, 16) * a0.w;
        pa += __shfl(ha,  4, 16) * a1.x; pa += __shfl(ha,  5, 16) * a1.y;
        pa += __shfl(ha,  6, 16) * a1.z; pa += __shfl(ha,  7, 16) * a1.w;
        pa += __shfl(ha,  8, 16) * a2.x; pa += __shfl(ha,  9, 16) * a2.y;
        pa += __shfl(ha, 10, 16) * a2.z; pa += __shfl(ha, 11, 16) * a2.w;
        pa += __shfl(ha, 12, 16) * a3.x; pa += __shfl(ha, 13, 16) * a3.y;
        pa += __shfl(ha, 14, 16) * a3.z; pa += __shfl(ha, 15, 16) * a3.w;
        pb  = __shfl(hb,  0, 16) * b0.x; pb += __shfl(hb,  1, 16) * b0.y;
        pb += __shfl(hb,  2, 16) * b0.z; pb += __shfl(hb,  3, 16) * b0.w;
        pb += __shfl(hb,  4, 16) * b1.x; pb += __shfl(hb,  5, 16) * b1.y;
        pb += __shfl(hb,  6, 16) * b1.z; pb += __shfl(hb,  7, 16) * b1.w;
        pb += __shfl(hb,  8, 16) * b2.x; pb += __shfl(hb,  9, 16) * b2.y;
        pb += __shfl(hb, 10, 16) * b2.z; pb += __shfl(hb, 11, 16) * b2.w;
        pb += __shfl(hb, 12, 16) * b3.x; pb += __shfl(hb, 13, 16) * b3.y;
        pb += __shfl(hb, 14, 16) * b3.z; pb += __shfl(hb, 15, 16) * b3.w;
        acc += __int_as_float(ra.y) * pa + __int_as_float(rb.y) * pb;
    }
    for (; j < end; j++) {
        int2 ra = recs[j];
        float ha = h[(ra.x & 0xFFFF) * EMB + c];
        const float4* wa = (const float4*)&w2s[(ra.x >> 16) * W2R + cbase];
        float4 a0 = wa[0], a1 = wa[1], a2 = wa[2], a3 = wa[3];
        float pa;
        pa  = __shfl(ha,  0, 16) * a0.x; pa += __shfl(ha,  1, 16) * a0.y;
        pa += __shfl(ha,  2, 16) * a0.z; pa += __shfl(ha,  3, 16) * a0.w;
        pa += __shfl(ha,  4, 16) * a1.x; pa += __shfl(ha,  5, 16) * a1.y;
        pa += __shfl(ha,  6, 16) * a1.z; pa += __shfl(ha,  7, 16) * a1.w;
        pa += __shfl(ha,  8, 16) * a2.x; pa += __shfl(ha,  9, 16) * a2.y;
        pa += __shfl(ha, 10, 16) * a2.z; pa += __shfl(ha, 11, 16) * a2.w;
        pa += __shfl(ha, 12, 16) * a3.x; pa += __shfl(ha, 13, 16) * a3.y;
        pa += __shfl(ha, 14, 16) * a3.z; pa += __shfl(ha, 15, 16) * a3.w;
        acc += __int_as_float(ra.y) * pa;
    }
    out[s * NCLS + c] = acc + bc;
}

extern "C" void kernel_launch(void* const* d_in, const int* in_sizes, int n_in,
                              void* d_out, int out_size, void* d_ws, size_t ws_size,
                              hipStream_t stream) {
    const int*   src    = (const int*)d_in[0];
    const int*   dst    = (const int*)d_in[1];
    const int*   rel    = (const int*)d_in[2];
    const float* comps1 = (const float*)d_in[3];
    const float* bases1 = (const float*)d_in[4];
    const float* comps2 = (const float*)d_in[5];
    const float* bases2 = (const float*)d_in[6];
    const float* bias1  = (const float*)d_in[7];
    const float* bias2  = (const float*)d_in[8];
    float* out = (float*)d_out;
    (void)in_sizes; (void)n_in; (void)out_size;

    char* ws = (char*)d_ws;
    size_t off_b = 0;
    // w1 region first; cnt aliases its head (cnt dead before k_w1 writes w1)
    float* w1     = (float*)(ws + off_b);
    int*   cnt    = (int*)(ws + off_b);   off_b += (size_t)R_TOT * NE_COL * 4;   // 131.2 MB
    int*   deg    = (int*)(ws + off_b);   off_b += (size_t)N_NODES * 4;
    int*   off    = (int*)(ws + off_b);   off_b += (size_t)(N_NODES + 1) * 4;
    int*   cursor = (int*)(ws + off_b);   off_b += (size_t)N_NODES * 4;
    int*   bsum   = (int*)(ws + off_b);   off_b += (size_t)256 * 4;
    int2*  recs   = (int2*)(ws + off_b);  off_b += (size_t)E_TOT * 8;
    float* h      = (float*)(ws + off_b); off_b += (size_t)NE_COL * 4;
    float* w2t    = (float*)(ws + off_b); off_b += (size_t)R_TOT * EMB * NCLS * 4;
    const bool materialize_w1 = (ws_size >= off_b);
    if (!materialize_w1) {
        off_b = 0;
        cnt    = (int*)(ws + off_b);   off_b += (size_t)R_TOT * N_NODES * 4;
        deg    = (int*)(ws + off_b);   off_b += (size_t)N_NODES * 4;
        off    = (int*)(ws + off_b);   off_b += (size_t)(N_NODES + 1) * 4;
        cursor = (int*)(ws + off_b);   off_b += (size_t)N_NODES * 4;
        bsum   = (int*)(ws + off_b);   off_b += (size_t)256 * 4;
        recs   = (int2*)(ws + off_b);  off_b += (size_t)E_TOT * 8;
        h      = (float*)(ws + off_b); off_b += (size_t)NE_COL * 4;
        w2t    = (float*)(ws + off_b); off_b += (size_t)R_TOT * EMB * NCLS * 4;
    }

    hipMemsetAsync(cnt, 0, (size_t)R_TOT * N_NODES * 4, stream);

    const int BLK = 256;
    const int g_edge = (E_TOT + BLK - 1) / BLK;       // 4102
    const int g_w1   = (NE_COL / 2 + BLK - 1) / BLK;  // 1563
    const int g_l1   = (N_NODES * 16) / BLK;          // 3125 (exact)
    const int g_l2   = (NE_COL + 1023) / 1024;        // 782

    k_count<<<g_edge, BLK, 0, stream>>>(src, dst, rel, cnt);
    k_degA<<<NBLK_N, 256, 0, stream>>>(cnt, deg, bsum);
    k_degB<<<1, 256, 0, stream>>>(bsum);
    k_degC<<<NBLK_N, 256, 0, stream>>>(deg, bsum, off, cursor);
    k_fill<<<g_edge, BLK, 0, stream>>>(src, dst, rel, cnt, cursor, recs);
    k_w2<<<R_TOT, EMB * NCLS, 0, stream>>>(comps2, bases2, w2t);

    if (materialize_w1) {
        k_w1<<<g_w1, BLK, 0, stream>>>(comps1, bases1, w1);   // overwrites cnt (dead)
        k_l1_gather<<<g_l1, BLK, 0, stream>>>(off, recs, w1, bias1, h);
    } else {
        k_l1_gather_fly<<<g_l1, BLK, 0, stream>>>(off, recs, comps1, bases1, bias1, h);
    }

    k_l2_gather<<<g_l2, 1024, 0, stream>>>(off, recs, h, w2t, bias2, out);
}

// Round 4
// 469.525 us; speedup vs baseline: 1.9458x; 1.9458x over previous
//
#include <hip/hip_runtime.h>

#define N_NODES 50000
#define N_RELSR 20
#define R_TOT   41          // 2*N_RELSR + 1
#define N_EDGES 500000
#define EMB     16
#define NCLS    16
#define NB      40
#define E_TOT   (2 * N_EDGES + N_NODES)   // 1,050,000
#define NE_COL  (N_NODES * EMB)           // 800,000
#define NBLK_N  ((N_NODES + 255) / 256)   // 196

// decode enriched edge i -> (s, o, r)
__device__ __forceinline__ void edge_decode(int i, const int* __restrict__ src,
                                            const int* __restrict__ dst,
                                            const int* __restrict__ rel,
                                            int& s, int& o, int& r) {
    if (i < N_EDGES) {
        s = src[i]; o = dst[i]; r = rel[i];
    } else if (i < 2 * N_EDGES) {
        int j = i - N_EDGES;
        s = dst[j]; o = src[j]; r = rel[j] + N_RELSR;
    } else {
        int n = i - 2 * N_EDGES;
        s = n; o = n; r = 2 * N_RELSR;
    }
}

// ---- K1: segment counts -----------------------------------------------------
__global__ void k_count(const int* __restrict__ src, const int* __restrict__ dst,
                        const int* __restrict__ rel, int* __restrict__ cnt) {
    int i = blockIdx.x * blockDim.x + threadIdx.x;
    if (i >= E_TOT) return;
    int s, o, r;
    edge_decode(i, src, dst, rel, s, o, r);
    atomicAdd(&cnt[r * N_NODES + s], 1);
}

// ---- K2a: deg[s] = sum_r cnt[r,s]; per-block sums ---------------------------
__global__ void k_degA(const int* __restrict__ cnt, int* __restrict__ deg,
                       int* __restrict__ bsum) {
    __shared__ int red[256];
    int t = threadIdx.x;
    int s = blockIdx.x * 256 + t;
    int d = 0;
    if (s < N_NODES) {
#pragma unroll
        for (int r = 0; r < R_TOT; r++) d += cnt[r * N_NODES + s];
        deg[s] = d;
    }
    red[t] = d;
    __syncthreads();
    for (int st = 128; st > 0; st >>= 1) {
        if (t < st) red[t] += red[t + st];
        __syncthreads();
    }
    if (t == 0) bsum[blockIdx.x] = red[0];
}

// ---- K2b: exclusive scan of 196 block sums (single tiny block) --------------
__global__ void k_degB(int* __restrict__ bsum) {
    __shared__ int sh[256];
    int t = threadIdx.x;
    int v = (t < NBLK_N) ? bsum[t] : 0;
    sh[t] = v;
    __syncthreads();
    for (int d = 1; d < 256; d <<= 1) {
        int x = (t >= d) ? sh[t - d] : 0;
        __syncthreads();
        sh[t] += x;
        __syncthreads();
    }
    if (t < NBLK_N) bsum[t] = sh[t] - v;   // exclusive
}

// ---- K2c: block-local scan of deg + apply block offset -> off, cursor -------
__global__ void k_degC(const int* __restrict__ deg, const int* __restrict__ bsum,
                       int* __restrict__ off, int* __restrict__ cursor) {
    __shared__ int sh[256];
    int t = threadIdx.x;
    int s = blockIdx.x * 256 + t;
    int d = (s < N_NODES) ? deg[s] : 0;
    sh[t] = d;
    __syncthreads();
    for (int dd = 1; dd < 256; dd <<= 1) {
        int x = (t >= dd) ? sh[t - dd] : 0;
        __syncthreads();
        sh[t] += x;
        __syncthreads();
    }
    int excl = sh[t] - d + bsum[blockIdx.x];
    if (s < N_NODES) { off[s] = excl; cursor[s] = excl; }
    if (s == 0) off[N_NODES] = E_TOT;
}

// ---- K3: fill CSR records {(r<<16)|o, v} sorted by s ------------------------
__global__ void k_fill(const int* __restrict__ src, const int* __restrict__ dst,
                       const int* __restrict__ rel, const int* __restrict__ cnt,
                       int* __restrict__ cursor, int2* __restrict__ recs) {
    int i = blockIdx.x * blockDim.x + threadIdx.x;
    if (i >= E_TOT) return;
    int s, o, r;
    edge_decode(i, src, dst, rel, s, o, r);
    float v = 1.0f / (float)cnt[r * N_NODES + s];
    int pos = atomicAdd(&cursor[s], 1);
    recs[pos] = make_int2((r << 16) | o, __float_as_int(v));
}

// ---- K4: w1[r,n,e] = sum_b comps1[r,b] * bases1[b,n,e] ----------------------
// Loop inversion vs round-3: per-thread state is acc[R_TOT] (the outputs),
// bases1 values are streamed and read exactly once. comps1 reads are
// wave-uniform -> SGPR s_load (zero VGPR cost). No spill.
__global__ void k_w1(const float* __restrict__ comps1, const float* __restrict__ bases1,
                     float* __restrict__ w1) {
    int j = blockIdx.x * blockDim.x + threadIdx.x;
    if (j >= NE_COL) return;
    float acc[R_TOT];
#pragma unroll
    for (int r = 0; r < R_TOT; r++) acc[r] = 0.f;
    for (int b = 0; b < NB; b++) {
        float bb = bases1[(size_t)b * NE_COL + j];
#pragma unroll
        for (int r = 0; r < R_TOT; r++) acc[r] += comps1[r * NB + b] * bb;
    }
#pragma unroll
    for (int r = 0; r < R_TOT; r++) w1[(size_t)r * NE_COL + j] = acc[r];
}

// ---- K5: w2t[r,c,e] = sum_b comps2[r,b] * bases2[b,e,c]  (transposed) -------
__global__ void k_w2(const float* __restrict__ comps2, const float* __restrict__ bases2,
                     float* __restrict__ w2t) {
    int r = blockIdx.x;        // 41 blocks
    int t = threadIdx.x;       // 256 = NCLS*EMB, t = c*16+e
    int c = t >> 4, e = t & 15;
    float acc = 0.f;
#pragma unroll 8
    for (int b = 0; b < NB; b++) acc += comps2[r * NB + b] * bases2[b * (EMB * NCLS) + e * NCLS + c];
    w2t[r * (EMB * NCLS) + t] = acc;
}

// ---- K6: layer-1 gather: h[s,e] = relu(bias1[e] + sum_j v*w1[r,o,e]) --------
// 4-way unroll to keep 4 random w1 gathers in flight per lane.
__global__ void k_l1_gather(const int* __restrict__ off, const int2* __restrict__ recs,
                            const float* __restrict__ w1, const float* __restrict__ bias1,
                            float* __restrict__ h) {
    int t = blockIdx.x * blockDim.x + threadIdx.x;     // N_NODES*16 exact
    int s = t >> 4, e = t & 15;
    int beg = off[s], end = off[s + 1];
    float acc = 0.f;
    int j = beg;
    for (; j + 3 < end; j += 4) {
        int2 r0 = recs[j], r1 = recs[j + 1], r2 = recs[j + 2], r3 = recs[j + 3];
        float f0 = w1[(size_t)(r0.x >> 16) * NE_COL + (r0.x & 0xFFFF) * EMB + e];
        float f1 = w1[(size_t)(r1.x >> 16) * NE_COL + (r1.x & 0xFFFF) * EMB + e];
        float f2 = w1[(size_t)(r2.x >> 16) * NE_COL + (r2.x & 0xFFFF) * EMB + e];
        float f3 = w1[(size_t)(r3.x >> 16) * NE_COL + (r3.x & 0xFFFF) * EMB + e];
        acc += __int_as_float(r0.y) * f0 + __int_as_float(r1.y) * f1 +
               __int_as_float(r2.y) * f2 + __int_as_float(r3.y) * f3;
    }
    for (; j < end; j++) {
        int2 rc = recs[j];
        acc += __int_as_float(rc.y) *
               w1[(size_t)(rc.x >> 16) * NE_COL + (rc.x & 0xFFFF) * EMB + e];
    }
    h[t] = fmaxf(acc + bias1[e], 0.f);
}

// ---- K6-alt (fallback if ws too small for w1): on-the-fly basis contraction -
__global__ void k_l1_gather_fly(const int* __restrict__ off, const int2* __restrict__ recs,
                                const float* __restrict__ comps1,
                                const float* __restrict__ bases1,
                                const float* __restrict__ bias1, float* __restrict__ h) {
    __shared__ float c1[R_TOT * NB];
    for (int q = threadIdx.x; q < R_TOT * NB; q += blockDim.x) c1[q] = comps1[q];
    __syncthreads();
    int t = blockIdx.x * blockDim.x + threadIdx.x;
    int s = t >> 4, e = t & 15;
    int beg = off[s], end = off[s + 1];
    float acc = 0.f;
    for (int j = beg; j < end; j++) {
        int2 rec = recs[j];
        int o = rec.x & 0xFFFF, r = rec.x >> 16;
        float v = __int_as_float(rec.y);
        const float* cr = &c1[r * NB];
        float w = 0.f;
#pragma unroll 8
        for (int b = 0; b < NB; b++) w += cr[b] * bases1[(size_t)b * NE_COL + o * EMB + e];
        acc += v * w;
    }
    h[t] = fmaxf(acc + bias1[e], 0.f);
}

// ---- K7: layer-2 gather: out[s,c] = bias2[c] + sum_j v * (h[o,:]·w2[r,:,c]) -
// w2 in LDS transposed [r][c][e], c-stride 20 (16B-aligned, 2-way banks only),
// r-stride 324. 4x ds_read_b128 per edge instead of 16 scalar reads.
#define W2C 20
#define W2R (16 * W2C + 4)    // 324
__global__ void k_l2_gather(const int* __restrict__ off, const int2* __restrict__ recs,
                            const float* __restrict__ h, const float* __restrict__ w2t,
                            const float* __restrict__ bias2, float* __restrict__ out) {
    __shared__ __align__(16) float w2s[R_TOT * W2R];   // 53,136 B
    for (int q = threadIdx.x; q < R_TOT * (EMB * NCLS); q += blockDim.x) {
        int r = q >> 8;
        int x = q & 255;
        int c = x >> 4, e = x & 15;
        w2s[r * W2R + c * W2C + e] = w2t[q];
    }
    __syncthreads();
    int t = blockIdx.x * blockDim.x + threadIdx.x;
    if (t >= NE_COL) return;
    int s = t >> 4, c = t & 15;
    int beg = off[s], end = off[s + 1];
    float bc = bias2[c];
    int cbase = c * W2C;
    float acc = 0.f;
    int j = beg;
    for (; j + 1 < end; j += 2) {
        int2 ra = recs[j], rb = recs[j + 1];
        float ha = h[(ra.x & 0xFFFF) * EMB + c];
        float hb = h[(rb.x & 0xFFFF) * EMB + c];
        const float4* wa = (const float4*)&w2s[(ra.x >> 16) * W2R + cbase];
        const float4* wb = (const float4*)&w2s[(rb.x >> 16) * W2R + cbase];
        float4 a0 = wa[0], a1 = wa[1], a2 = wa[2], a3 = wa[3];
        float4 b0 = wb[0], b1 = wb[1], b2 = wb[2], b3 = wb[3];
        float pa, pb;
        pa  = __shfl(ha,  0, 16) * a0.x; pa += __shfl(ha,  1, 16) * a0.y;
        pa += __shfl(ha,  2, 16) * a0.z; pa += __shfl(ha,  3, 16) * a0.w;
        pa += __shfl(ha,  4, 16) * a1.x; pa += __shfl(ha,  5, 16) * a1.y;
        pa += __shfl(ha,  6, 16) * a1.z; pa += __shfl(ha,  7, 16) * a1.w;
        pa += __shfl(ha,  8, 16) * a2.x; pa += __shfl(ha,  9, 16) * a2.y;
        pa += __shfl(ha, 10, 16) * a2.z; pa += __shfl(ha, 11, 16) * a2.w;
        pa += __shfl(ha, 12, 16) * a3.x; pa += __shfl(ha, 13, 16) * a3.y;
        pa += __shfl(ha, 14, 16) * a3.z; pa += __shfl(ha, 15, 16) * a3.w;
        pb  = __shfl(hb,  0, 16) * b0.x; pb += __shfl(hb,  1, 16) * b0.y;
        pb += __shfl(hb,  2, 16) * b0.z; pb += __shfl(hb,  3, 16) * b0.w;
        pb += __shfl(hb,  4, 16) * b1.x; pb += __shfl(hb,  5, 16) * b1.y;
        pb += __shfl(hb,  6, 16) * b1.z; pb += __shfl(hb,  7, 16) * b1.w;
        pb += __shfl(hb,  8, 16) * b2.x; pb += __shfl(hb,  9, 16) * b2.y;
        pb += __shfl(hb, 10, 16) * b2.z; pb += __shfl(hb, 11, 16) * b2.w;
        pb += __shfl(hb, 12, 16) * b3.x; pb += __shfl(hb, 13, 16) * b3.y;
        pb += __shfl(hb, 14, 16) * b3.z; pb += __shfl(hb, 15, 16) * b3.w;
        acc += __int_as_float(ra.y) * pa + __int_as_float(rb.y) * pb;
    }
    for (; j < end; j++) {
        int2 ra = recs[j];
        float ha = h[(ra.x & 0xFFFF) * EMB + c];
        const float4* wa = (const float4*)&w2s[(ra.x >> 16) * W2R + cbase];
        float4 a0 = wa[0], a1 = wa[1], a2 = wa[2], a3 = wa[3];
        float pa;
        pa  = __shfl(ha,  0, 16) * a0.x; pa += __shfl(ha,  1, 16) * a0.y;
        pa += __shfl(ha,  2, 16) * a0.z; pa += __shfl(ha,  3, 16) * a0.w;
        pa += __shfl(ha,  4, 16) * a1.x; pa += __shfl(ha,  5, 16) * a1.y;
        pa += __shfl(ha,  6, 16) * a1.z; pa += __shfl(ha,  7, 16) * a1.w;
        pa += __shfl(ha,  8, 16) * a2.x; pa += __shfl(ha,  9, 16) * a2.y;
        pa += __shfl(ha, 10, 16) * a2.z; pa += __shfl(ha, 11, 16) * a2.w;
        pa += __shfl(ha, 12, 16) * a3.x; pa += __shfl(ha, 13, 16) * a3.y;
        pa += __shfl(ha, 14, 16) * a3.z; pa += __shfl(ha, 15, 16) * a3.w;
        acc += __int_as_float(ra.y) * pa;
    }
    out[s * NCLS + c] = acc + bc;
}

extern "C" void kernel_launch(void* const* d_in, const int* in_sizes, int n_in,
                              void* d_out, int out_size, void* d_ws, size_t ws_size,
                              hipStream_t stream) {
    const int*   src    = (const int*)d_in[0];
    const int*   dst    = (const int*)d_in[1];
    const int*   rel    = (const int*)d_in[2];
    const float* comps1 = (const float*)d_in[3];
    const float* bases1 = (const float*)d_in[4];
    const float* comps2 = (const float*)d_in[5];
    const float* bases2 = (const float*)d_in[6];
    const float* bias1  = (const float*)d_in[7];
    const float* bias2  = (const float*)d_in[8];
    float* out = (float*)d_out;
    (void)in_sizes; (void)n_in; (void)out_size;

    char* ws = (char*)d_ws;
    size_t off_b = 0;
    // w1 region first; cnt aliases its head (cnt dead before k_w1 writes w1)
    float* w1     = (float*)(ws + off_b);
    int*   cnt    = (int*)(ws + off_b);   off_b += (size_t)R_TOT * NE_COL * 4;   // 131.2 MB
    int*   deg    = (int*)(ws + off_b);   off_b += (size_t)N_NODES * 4;
    int*   off    = (int*)(ws + off_b);   off_b += (size_t)(N_NODES + 1) * 4;
    int*   cursor = (int*)(ws + off_b);   off_b += (size_t)N_NODES * 4;
    int*   bsum   = (int*)(ws + off_b);   off_b += (size_t)256 * 4;
    int2*  recs   = (int2*)(ws + off_b);  off_b += (size_t)E_TOT * 8;
    float* h      = (float*)(ws + off_b); off_b += (size_t)NE_COL * 4;
    float* w2t    = (float*)(ws + off_b); off_b += (size_t)R_TOT * EMB * NCLS * 4;
    const bool materialize_w1 = (ws_size >= off_b);
    if (!materialize_w1) {
        off_b = 0;
        cnt    = (int*)(ws + off_b);   off_b += (size_t)R_TOT * N_NODES * 4;
        deg    = (int*)(ws + off_b);   off_b += (size_t)N_NODES * 4;
        off    = (int*)(ws + off_b);   off_b += (size_t)(N_NODES + 1) * 4;
        cursor = (int*)(ws + off_b);   off_b += (size_t)N_NODES * 4;
        bsum   = (int*)(ws + off_b);   off_b += (size_t)256 * 4;
        recs   = (int2*)(ws + off_b);  off_b += (size_t)E_TOT * 8;
        h      = (float*)(ws + off_b); off_b += (size_t)NE_COL * 4;
        w2t    = (float*)(ws + off_b); off_b += (size_t)R_TOT * EMB * NCLS * 4;
    }

    hipMemsetAsync(cnt, 0, (size_t)R_TOT * N_NODES * 4, stream);

    const int BLK = 256;
    const int g_edge = (E_TOT + BLK - 1) / BLK;       // 4102
    const int g_col  = (NE_COL + BLK - 1) / BLK;      // 3125
    const int g_l1   = (N_NODES * 16) / BLK;          // 3125 (exact)
    const int g_l2   = (NE_COL + 1023) / 1024;        // 782

    k_count<<<g_edge, BLK, 0, stream>>>(src, dst, rel, cnt);
    k_degA<<<NBLK_N, 256, 0, stream>>>(cnt, deg, bsum);
    k_degB<<<1, 256, 0, stream>>>(bsum);
    k_degC<<<NBLK_N, 256, 0, stream>>>(deg, bsum, off, cursor);
    k_fill<<<g_edge, BLK, 0, stream>>>(src, dst, rel, cnt, cursor, recs);
    k_w2<<<R_TOT, EMB * NCLS, 0, stream>>>(comps2, bases2, w2t);

    if (materialize_w1) {
        k_w1<<<g_col, BLK, 0, stream>>>(comps1, bases1, w1);   // overwrites cnt (dead)
        k_l1_gather<<<g_l1, BLK, 0, stream>>>(off, recs, w1, bias1, h);
    } else {
        k_l1_gather_fly<<<g_l1, BLK, 0, stream>>>(off, recs, comps1, bases1, bias1, h);
    }

    k_l2_gather<<<g_l2, 1024, 0, stream>>>(off, recs, h, w2t, bias2, out);
}

// Round 5
// 433.795 us; speedup vs baseline: 2.1061x; 1.0824x over previous
//
#include <hip/hip_runtime.h>

#define N_NODES 50000
#define N_RELSR 20
#define R_TOT   41          // 2*N_RELSR + 1
#define N_EDGES 500000
#define EMB     16
#define NCLS    16
#define NB      40
#define E_TOT   (2 * N_EDGES + N_NODES)   // 1,050,000
#define NE_COL  (N_NODES * EMB)           // 800,000
#define NBLK_N  ((N_NODES + 255) / 256)   // 196

// decode enriched edge i -> (s, o, r)
__device__ __forceinline__ void edge_decode(int i, const int* __restrict__ src,
                                            const int* __restrict__ dst,
                                            const int* __restrict__ rel,
                                            int& s, int& o, int& r) {
    if (i < N_EDGES) {
        s = src[i]; o = dst[i]; r = rel[i];
    } else if (i < 2 * N_EDGES) {
        int j = i - N_EDGES;
        s = dst[j]; o = src[j]; r = rel[j] + N_RELSR;
    } else {
        int n = i - 2 * N_EDGES;
        s = n; o = n; r = 2 * N_RELSR;
    }
}

// cnt2[idx] = { count, roff }  (roff = global exclusive prefix position)

// ---- K1: segment counts; also record each edge's rank within its segment ---
__global__ void k_count(const int* __restrict__ src, const int* __restrict__ dst,
                        const int* __restrict__ rel, int2* __restrict__ cnt2,
                        int* __restrict__ rank) {
    int i = blockIdx.x * blockDim.x + threadIdx.x;
    if (i >= E_TOT) return;
    int s, o, r;
    edge_decode(i, src, dst, rel, s, o, r);
    rank[i] = atomicAdd(&cnt2[r * N_NODES + s].x, 1);
}

// ---- K2a: deg[s] = sum_r cnt[r,s]; local r-prefix into .y; per-block sums ---
__global__ void k_degA(int2* __restrict__ cnt2, int* __restrict__ deg,
                       int* __restrict__ bsum) {
    __shared__ int red[256];
    int t = threadIdx.x;
    int s = blockIdx.x * 256 + t;
    int run = 0;
    if (s < N_NODES) {
        for (int r = 0; r < R_TOT; r++) {
            int idx = r * N_NODES + s;
            int2 val = cnt2[idx];
            val.y = run;              // local exclusive prefix over r
            cnt2[idx] = val;
            run += val.x;
        }
        deg[s] = run;
    }
    red[t] = run;
    __syncthreads();
    for (int st = 128; st > 0; st >>= 1) {
        if (t < st) red[t] += red[t + st];
        __syncthreads();
    }
    if (t == 0) bsum[blockIdx.x] = red[0];
}

// ---- K2b: exclusive scan of 196 block sums (single tiny block) --------------
__global__ void k_degB(int* __restrict__ bsum) {
    __shared__ int sh[256];
    int t = threadIdx.x;
    int v = (t < NBLK_N) ? bsum[t] : 0;
    sh[t] = v;
    __syncthreads();
    for (int d = 1; d < 256; d <<= 1) {
        int x = (t >= d) ? sh[t - d] : 0;
        __syncthreads();
        sh[t] += x;
        __syncthreads();
    }
    if (t < NBLK_N) bsum[t] = sh[t] - v;   // exclusive
}

// ---- K2c: block-local scan of deg -> off; add global base into cnt2.y -------
__global__ void k_degC(const int* __restrict__ deg, const int* __restrict__ bsum,
                       int* __restrict__ off, int2* __restrict__ cnt2) {
    __shared__ int sh[256];
    int t = threadIdx.x;
    int s = blockIdx.x * 256 + t;
    int d = (s < N_NODES) ? deg[s] : 0;
    sh[t] = d;
    __syncthreads();
    for (int dd = 1; dd < 256; dd <<= 1) {
        int x = (t >= dd) ? sh[t - dd] : 0;
        __syncthreads();
        sh[t] += x;
        __syncthreads();
    }
    int excl = sh[t] - d + bsum[blockIdx.x];
    if (s < N_NODES) {
        off[s] = excl;
        int* base = (int*)cnt2;
        for (int r = 0; r < R_TOT; r++) {
            base[2 * (r * N_NODES + s) + 1] += excl;
        }
    }
    if (s == 0) off[N_NODES] = E_TOT;
}

// ---- K3: fill CSR records {(r<<16)|o, v} sorted by (s, r); no atomics -------
__global__ void k_fill(const int* __restrict__ src, const int* __restrict__ dst,
                       const int* __restrict__ rel, const int2* __restrict__ cnt2,
                       const int* __restrict__ rank, int2* __restrict__ recs) {
    int i = blockIdx.x * blockDim.x + threadIdx.x;
    if (i >= E_TOT) return;
    int s, o, r;
    edge_decode(i, src, dst, rel, s, o, r);
    int2 cr = cnt2[r * N_NODES + s];
    float v = 1.0f / (float)cr.x;
    recs[cr.y + rank[i]] = make_int2((r << 16) | o, __float_as_int(v));
}

// ---- K4: w1[r,n,e] = sum_b comps1[r,b] * bases1[b,n,e]  (float2) ------------
// acc[R_TOT] float2 ~ 96 VGPR; launch_bounds prevents the 64-VGPR spill cap.
__global__ void __launch_bounds__(256, 2)
k_w1(const float* __restrict__ comps1, const float* __restrict__ bases1,
     float* __restrict__ w1) {
    int j = blockIdx.x * blockDim.x + threadIdx.x;
    if (j >= NE_COL / 2) return;
    const float2* b2 = (const float2*)bases1;
    float2 acc[R_TOT];
#pragma unroll
    for (int r = 0; r < R_TOT; r++) { acc[r].x = 0.f; acc[r].y = 0.f; }
    for (int b = 0; b < NB; b++) {
        float2 bb = b2[(size_t)b * (NE_COL / 2) + j];
#pragma unroll
        for (int r = 0; r < R_TOT; r++) {
            float cc = comps1[r * NB + b];
            acc[r].x += cc * bb.x;
            acc[r].y += cc * bb.y;
        }
    }
    float2* w1p = (float2*)w1;
#pragma unroll
    for (int r = 0; r < R_TOT; r++) w1p[(size_t)r * (NE_COL / 2) + j] = acc[r];
}

// ---- K5: w2t[r,c,e] = sum_b comps2[r,b] * bases2[b,e,c]  (transposed) -------
__global__ void k_w2(const float* __restrict__ comps2, const float* __restrict__ bases2,
                     float* __restrict__ w2t) {
    int r = blockIdx.x;        // 41 blocks
    int t = threadIdx.x;       // 256 = NCLS*EMB, t = c*16+e
    int c = t >> 4, e = t & 15;
    float acc = 0.f;
#pragma unroll 8
    for (int b = 0; b < NB; b++) acc += comps2[r * NB + b] * bases2[b * (EMB * NCLS) + e * NCLS + c];
    w2t[r * (EMB * NCLS) + t] = acc;
}

// ---- K6: layer-1 gather: h[s,e] = relu(bias1[e] + sum_j v*w1[r,o,e]) --------
__global__ void k_l1_gather(const int* __restrict__ off, const int2* __restrict__ recs,
                            const float* __restrict__ w1, const float* __restrict__ bias1,
                            float* __restrict__ h) {
    int t = blockIdx.x * blockDim.x + threadIdx.x;     // N_NODES*16 exact
    int s = t >> 4, e = t & 15;
    int beg = off[s], end = off[s + 1];
    float acc = 0.f;
    int j = beg;
    for (; j + 3 < end; j += 4) {
        int2 r0 = recs[j], r1 = recs[j + 1], r2 = recs[j + 2], r3 = recs[j + 3];
        float f0 = w1[(size_t)(r0.x >> 16) * NE_COL + (r0.x & 0xFFFF) * EMB + e];
        float f1 = w1[(size_t)(r1.x >> 16) * NE_COL + (r1.x & 0xFFFF) * EMB + e];
        float f2 = w1[(size_t)(r2.x >> 16) * NE_COL + (r2.x & 0xFFFF) * EMB + e];
        float f3 = w1[(size_t)(r3.x >> 16) * NE_COL + (r3.x & 0xFFFF) * EMB + e];
        acc += __int_as_float(r0.y) * f0 + __int_as_float(r1.y) * f1 +
               __int_as_float(r2.y) * f2 + __int_as_float(r3.y) * f3;
    }
    for (; j < end; j++) {
        int2 rc = recs[j];
        acc += __int_as_float(rc.y) *
               w1[(size_t)(rc.x >> 16) * NE_COL + (rc.x & 0xFFFF) * EMB + e];
    }
    h[t] = fmaxf(acc + bias1[e], 0.f);
}

// ---- K6-alt (fallback if ws too small for w1): on-the-fly basis contraction -
__global__ void k_l1_gather_fly(const int* __restrict__ off, const int2* __restrict__ recs,
                                const float* __restrict__ comps1,
                                const float* __restrict__ bases1,
                                const float* __restrict__ bias1, float* __restrict__ h) {
    __shared__ float c1[R_TOT * NB];
    for (int q = threadIdx.x; q < R_TOT * NB; q += blockDim.x) c1[q] = comps1[q];
    __syncthreads();
    int t = blockIdx.x * blockDim.x + threadIdx.x;
    int s = t >> 4, e = t & 15;
    int beg = off[s], end = off[s + 1];
    float acc = 0.f;
    for (int j = beg; j < end; j++) {
        int2 rec = recs[j];
        int o = rec.x & 0xFFFF, r = rec.x >> 16;
        float v = __int_as_float(rec.y);
        const float* cr = &c1[r * NB];
        float w = 0.f;
#pragma unroll 8
        for (int b = 0; b < NB; b++) w += cr[b] * bases1[(size_t)b * NE_COL + o * EMB + e];
        acc += v * w;
    }
    h[t] = fmaxf(acc + bias1[e], 0.f);
}

// ---- K7: layer-2 gather, no shfl: all 16 lanes of an edge-group load the ----
// same 64B h[o,:] row (L1 broadcast) and dot it with their w2 column from LDS.
#define W2C 20
#define W2R (16 * W2C + 4)    // 324
__global__ void k_l2_gather(const int* __restrict__ off, const int2* __restrict__ recs,
                            const float* __restrict__ h, const float* __restrict__ w2t,
                            const float* __restrict__ bias2, float* __restrict__ out) {
    __shared__ __align__(16) float w2s[R_TOT * W2R];   // 53,136 B -> 3 blocks/CU @512
    for (int q = threadIdx.x; q < R_TOT * (EMB * NCLS); q += blockDim.x) {
        int r = q >> 8;
        int x = q & 255;
        int c = x >> 4, e = x & 15;
        w2s[r * W2R + c * W2C + e] = w2t[q];
    }
    __syncthreads();
    int t = blockIdx.x * blockDim.x + threadIdx.x;
    if (t >= NE_COL) return;
    int s = t >> 4, c = t & 15;
    int beg = off[s], end = off[s + 1];
    int cbase = c * W2C;
    float acc = 0.f;
    int j = beg;
    for (; j + 1 < end; j += 2) {
        int2 ra = recs[j], rb = recs[j + 1];
        const float4* ha = (const float4*)(h + (size_t)(ra.x & 0xFFFF) * EMB);
        const float4* hb = (const float4*)(h + (size_t)(rb.x & 0xFFFF) * EMB);
        float4 h0 = ha[0], h1 = ha[1], h2 = ha[2], h3 = ha[3];
        float4 g0 = hb[0], g1 = hb[1], g2 = hb[2], g3 = hb[3];
        const float4* wa = (const float4*)&w2s[(ra.x >> 16) * W2R + cbase];
        const float4* wb = (const float4*)&w2s[(rb.x >> 16) * W2R + cbase];
        float4 a0 = wa[0], a1 = wa[1], a2 = wa[2], a3 = wa[3];
        float4 b0 = wb[0], b1 = wb[1], b2 = wb[2], b3 = wb[3];
        float da, db;
        da  = h0.x * a0.x; da = fmaf(h0.y, a0.y, da); da = fmaf(h0.z, a0.z, da); da = fmaf(h0.w, a0.w, da);
        da = fmaf(h1.x, a1.x, da); da = fmaf(h1.y, a1.y, da); da = fmaf(h1.z, a1.z, da); da = fmaf(h1.w, a1.w, da);
        da = fmaf(h2.x, a2.x, da); da = fmaf(h2.y, a2.y, da); da = fmaf(h2.z, a2.z, da); da = fmaf(h2.w, a2.w, da);
        da = fmaf(h3.x, a3.x, da); da = fmaf(h3.y, a3.y, da); da = fmaf(h3.z, a3.z, da); da = fmaf(h3.w, a3.w, da);
        db  = g0.x * b0.x; db = fmaf(g0.y, b0.y, db); db = fmaf(g0.z, b0.z, db); db = fmaf(g0.w, b0.w, db);
        db = fmaf(g1.x, b1.x, db); db = fmaf(g1.y, b1.y, db); db = fmaf(g1.z, b1.z, db); db = fmaf(g1.w, b1.w, db);
        db = fmaf(g2.x, b2.x, db); db = fmaf(g2.y, b2.y, db); db = fmaf(g2.z, b2.z, db); db = fmaf(g2.w, b2.w, db);
        db = fmaf(g3.x, b3.x, db); db = fmaf(g3.y, b3.y, db); db = fmaf(g3.z, b3.z, db); db = fmaf(g3.w, b3.w, db);
        acc = fmaf(__int_as_float(ra.y), da, acc);
        acc = fmaf(__int_as_float(rb.y), db, acc);
    }
    for (; j < end; j++) {
        int2 ra = recs[j];
        const float4* ha = (const float4*)(h + (size_t)(ra.x & 0xFFFF) * EMB);
        float4 h0 = ha[0], h1 = ha[1], h2 = ha[2], h3 = ha[3];
        const float4* wa = (const float4*)&w2s[(ra.x >> 16) * W2R + cbase];
        float4 a0 = wa[0], a1 = wa[1], a2 = wa[2], a3 = wa[3];
        float da;
        da  = h0.x * a0.x; da = fmaf(h0.y, a0.y, da); da = fmaf(h0.z, a0.z, da); da = fmaf(h0.w, a0.w, da);
        da = fmaf(h1.x, a1.x, da); da = fmaf(h1.y, a1.y, da); da = fmaf(h1.z, a1.z, da); da = fmaf(h1.w, a1.w, da);
        da = fmaf(h2.x, a2.x, da); da = fmaf(h2.y, a2.y, da); da = fmaf(h2.z, a2.z, da); da = fmaf(h2.w, a2.w, da);
        da = fmaf(h3.x, a3.x, da); da = fmaf(h3.y, a3.y, da); da = fmaf(h3.z, a3.z, da); da = fmaf(h3.w, a3.w, da);
        acc = fmaf(__int_as_float(ra.y), da, acc);
    }
    out[s * NCLS + c] = acc + bias2[c];
}

static inline size_t align64(size_t x) { return (x + 63) & ~(size_t)63; }

extern "C" void kernel_launch(void* const* d_in, const int* in_sizes, int n_in,
                              void* d_out, int out_size, void* d_ws, size_t ws_size,
                              hipStream_t stream) {
    const int*   src    = (const int*)d_in[0];
    const int*   dst    = (const int*)d_in[1];
    const int*   rel    = (const int*)d_in[2];
    const float* comps1 = (const float*)d_in[3];
    const float* bases1 = (const float*)d_in[4];
    const float* comps2 = (const float*)d_in[5];
    const float* bases2 = (const float*)d_in[6];
    const float* bias1  = (const float*)d_in[7];
    const float* bias2  = (const float*)d_in[8];
    float* out = (float*)d_out;
    (void)in_sizes; (void)n_in; (void)out_size;

    char* ws = (char*)d_ws;
    size_t off_b = 0;
    // w1 region first; cnt2 + rank alias its head (both dead before k_w1 runs)
    float* w1   = (float*)ws;
    int2*  cnt2 = (int2*)ws;                                  // 16.4 MB
    int*   rank = (int*)(ws + align64((size_t)R_TOT * N_NODES * 8));  // 4.2 MB
    off_b = align64((size_t)R_TOT * NE_COL * 4);              // 131.2 MB
    int*   deg  = (int*)(ws + off_b);  off_b = align64(off_b + (size_t)N_NODES * 4);
    int*   off  = (int*)(ws + off_b);  off_b = align64(off_b + (size_t)(N_NODES + 1) * 4);
    int*   bsum = (int*)(ws + off_b);  off_b = align64(off_b + (size_t)256 * 4);
    int2*  recs = (int2*)(ws + off_b); off_b = align64(off_b + (size_t)E_TOT * 8);
    float* h    = (float*)(ws + off_b); off_b = align64(off_b + (size_t)NE_COL * 4);
    float* w2t  = (float*)(ws + off_b); off_b = align64(off_b + (size_t)R_TOT * EMB * NCLS * 4);
    const bool materialize_w1 = (ws_size >= off_b);
    if (!materialize_w1) {
        off_b = 0;
        cnt2 = (int2*)(ws + off_b);  off_b = align64(off_b + (size_t)R_TOT * N_NODES * 8);
        rank = (int*)(ws + off_b);   off_b = align64(off_b + (size_t)E_TOT * 4);
        deg  = (int*)(ws + off_b);   off_b = align64(off_b + (size_t)N_NODES * 4);
        off  = (int*)(ws + off_b);   off_b = align64(off_b + (size_t)(N_NODES + 1) * 4);
        bsum = (int*)(ws + off_b);   off_b = align64(off_b + (size_t)256 * 4);
        recs = (int2*)(ws + off_b);  off_b = align64(off_b + (size_t)E_TOT * 8);
        h    = (float*)(ws + off_b); off_b = align64(off_b + (size_t)NE_COL * 4);
        w2t  = (float*)(ws + off_b); off_b = align64(off_b + (size_t)R_TOT * EMB * NCLS * 4);
    }

    // zero counts (.x of cnt2; .y overwritten by k_degA)
    hipMemsetAsync(cnt2, 0, (size_t)R_TOT * N_NODES * 8, stream);

    const int BLK = 256;
    const int g_edge = (E_TOT + BLK - 1) / BLK;           // 4102
    const int g_w1   = (NE_COL / 2 + BLK - 1) / BLK;      // 1563
    const int g_l1   = (N_NODES * 16) / BLK;              // 3125 (exact)
    const int g_l2   = (NE_COL + 511) / 512;              // 1563

    k_count<<<g_edge, BLK, 0, stream>>>(src, dst, rel, cnt2, rank);
    k_degA<<<NBLK_N, 256, 0, stream>>>(cnt2, deg, bsum);
    k_degB<<<1, 256, 0, stream>>>(bsum);
    k_degC<<<NBLK_N, 256, 0, stream>>>(deg, bsum, off, cnt2);
    k_fill<<<g_edge, BLK, 0, stream>>>(src, dst, rel, cnt2, rank, recs);
    k_w2<<<R_TOT, EMB * NCLS, 0, stream>>>(comps2, bases2, w2t);

    if (materialize_w1) {
        k_w1<<<g_w1, BLK, 0, stream>>>(comps1, bases1, w1);   // overwrites cnt2/rank (dead)
        k_l1_gather<<<g_l1, BLK, 0, stream>>>(off, recs, w1, bias1, h);
    } else {
        k_l1_gather_fly<<<g_l1, BLK, 0, stream>>>(off, recs, comps1, bases1, bias1, h);
    }

    k_l2_gather<<<g_l2, 512, 0, stream>>>(off, recs, h, w2t, bias2, out);
}

// Round 6
// 412.379 us; speedup vs baseline: 2.2155x; 1.0519x over previous
//
#include <hip/hip_runtime.h>

#define N_NODES 50000
#define N_RELSR 20
#define R_TOT   41          // 2*N_RELSR + 1
#define N_EDGES 500000
#define EMB     16
#define NCLS    16
#define NB      40
#define E_TOT   (2 * N_EDGES + N_NODES)   // 1,050,000
#define NE_COL  (N_NODES * EMB)           // 800,000
#define NBLK_N  ((N_NODES + 255) / 256)   // 196

// f32 -> bf16 round-to-nearest-even (manual, no header dependency)
__device__ __forceinline__ unsigned short f2bf(float f) {
    unsigned u = __float_as_uint(f);
    u += 0x7FFFu + ((u >> 16) & 1u);
    return (unsigned short)(u >> 16);
}
__device__ __forceinline__ float bf2f(unsigned short b) {
    return __uint_as_float((unsigned)b << 16);
}

// decode enriched edge i -> (s, o, r)
__device__ __forceinline__ void edge_decode(int i, const int* __restrict__ src,
                                            const int* __restrict__ dst,
                                            const int* __restrict__ rel,
                                            int& s, int& o, int& r) {
    if (i < N_EDGES) {
        s = src[i]; o = dst[i]; r = rel[i];
    } else if (i < 2 * N_EDGES) {
        int j = i - N_EDGES;
        s = dst[j]; o = src[j]; r = rel[j] + N_RELSR;
    } else {
        int n = i - 2 * N_EDGES;
        s = n; o = n; r = 2 * N_RELSR;
    }
}

// cnt2[idx] = { count, local r-prefix within node s }

// ---- K1: segment counts; also record each edge's rank within its segment ---
__global__ void k_count(const int* __restrict__ src, const int* __restrict__ dst,
                        const int* __restrict__ rel, int2* __restrict__ cnt2,
                        int* __restrict__ rank) {
    int i = blockIdx.x * blockDim.x + threadIdx.x;
    if (i >= E_TOT) return;
    int s, o, r;
    edge_decode(i, src, dst, rel, s, o, r);
    rank[i] = atomicAdd(&cnt2[r * N_NODES + s].x, 1);
}

// ---- K2a: deg[s] = sum_r cnt[r,s]; local r-prefix into .y; per-block sums ---
__global__ void k_degA(int2* __restrict__ cnt2, int* __restrict__ deg,
                       int* __restrict__ bsum) {
    __shared__ int red[256];
    int t = threadIdx.x;
    int s = blockIdx.x * 256 + t;
    int run = 0;
    if (s < N_NODES) {
        for (int r = 0; r < R_TOT; r++) {
            int idx = r * N_NODES + s;
            int2 val = cnt2[idx];
            val.y = run;              // local exclusive prefix over r
            cnt2[idx] = val;
            run += val.x;
        }
        deg[s] = run;
    }
    red[t] = run;
    __syncthreads();
    for (int st = 128; st > 0; st >>= 1) {
        if (t < st) red[t] += red[t + st];
        __syncthreads();
    }
    if (t == 0) bsum[blockIdx.x] = red[0];
}

// ---- K2b: exclusive scan of 196 block sums (single tiny block) --------------
__global__ void k_degB(int* __restrict__ bsum) {
    __shared__ int sh[256];
    int t = threadIdx.x;
    int v = (t < NBLK_N) ? bsum[t] : 0;
    sh[t] = v;
    __syncthreads();
    for (int d = 1; d < 256; d <<= 1) {
        int x = (t >= d) ? sh[t - d] : 0;
        __syncthreads();
        sh[t] += x;
        __syncthreads();
    }
    if (t < NBLK_N) bsum[t] = sh[t] - v;   // exclusive
}

// ---- K2c: block-local scan of deg -> off (global CSR offsets) ---------------
__global__ void k_degC(const int* __restrict__ deg, const int* __restrict__ bsum,
                       int* __restrict__ off) {
    __shared__ int sh[256];
    int t = threadIdx.x;
    int s = blockIdx.x * 256 + t;
    int d = (s < N_NODES) ? deg[s] : 0;
    sh[t] = d;
    __syncthreads();
    for (int dd = 1; dd < 256; dd <<= 1) {
        int x = (t >= dd) ? sh[t - dd] : 0;
        __syncthreads();
        sh[t] += x;
        __syncthreads();
    }
    int excl = sh[t] - d + bsum[blockIdx.x];
    if (s < N_NODES) off[s] = excl;
    if (s == 0) off[N_NODES] = E_TOT;
}

// ---- K3: fill CSR records {(r<<16)|o, v} sorted by (s, r); no atomics -------
__global__ void k_fill(const int* __restrict__ src, const int* __restrict__ dst,
                       const int* __restrict__ rel, const int2* __restrict__ cnt2,
                       const int* __restrict__ rank, const int* __restrict__ off,
                       int2* __restrict__ recs) {
    int i = blockIdx.x * blockDim.x + threadIdx.x;
    if (i >= E_TOT) return;
    int s, o, r;
    edge_decode(i, src, dst, rel, s, o, r);
    int2 cr = cnt2[r * N_NODES + s];
    float v = 1.0f / (float)cr.x;
    recs[off[s] + cr.y + rank[i]] = make_int2((r << 16) | o, __float_as_int(v));
}

// ---- K4: w1[r,n,e] = sum_b comps1[r,b] * bases1[b,n,e]  -> bf16 -------------
// thread j handles 2 consecutive elements; stores packed bf16x2 as uint.
__global__ void __launch_bounds__(256, 2)
k_w1(const float* __restrict__ comps1, const float* __restrict__ bases1,
     unsigned* __restrict__ w1p) {
    int j = blockIdx.x * blockDim.x + threadIdx.x;
    if (j >= NE_COL / 2) return;
    const float2* b2 = (const float2*)bases1;
    float2 acc[R_TOT];
#pragma unroll
    for (int r = 0; r < R_TOT; r++) { acc[r].x = 0.f; acc[r].y = 0.f; }
    for (int b = 0; b < NB; b++) {
        float2 bb = b2[(size_t)b * (NE_COL / 2) + j];
#pragma unroll
        for (int r = 0; r < R_TOT; r++) {
            float cc = comps1[r * NB + b];
            acc[r].x += cc * bb.x;
            acc[r].y += cc * bb.y;
        }
    }
#pragma unroll
    for (int r = 0; r < R_TOT; r++) {
        unsigned pk = ((unsigned)f2bf(acc[r].y) << 16) | (unsigned)f2bf(acc[r].x);
        w1p[(size_t)r * (NE_COL / 2) + j] = pk;
    }
}

// ---- K5: w2t[r,c,e] = sum_b comps2[r,b] * bases2[b,e,c]  (transposed) -------
__global__ void k_w2(const float* __restrict__ comps2, const float* __restrict__ bases2,
                     float* __restrict__ w2t) {
    int r = blockIdx.x;        // 41 blocks
    int t = threadIdx.x;       // 256 = NCLS*EMB, t = c*16+e
    int c = t >> 4, e = t & 15;
    float acc = 0.f;
#pragma unroll 8
    for (int b = 0; b < NB; b++) acc += comps2[r * NB + b] * bases2[b * (EMB * NCLS) + e * NCLS + c];
    w2t[r * (EMB * NCLS) + t] = acc;
}

// ---- K6: layer-1 gather: h[s,e] = relu(bias1[e] + sum_j v*w1[r,o,e]) --------
// w1 is bf16 (fully L3-resident at 65.6 MB); 4-way unroll for latency.
__global__ void k_l1_gather(const int* __restrict__ off, const int2* __restrict__ recs,
                            const unsigned short* __restrict__ w1,
                            const float* __restrict__ bias1, float* __restrict__ h) {
    int t = blockIdx.x * blockDim.x + threadIdx.x;     // N_NODES*16 exact
    int s = t >> 4, e = t & 15;
    int beg = off[s], end = off[s + 1];
    float acc = 0.f;
    int j = beg;
    for (; j + 3 < end; j += 4) {
        int2 r0 = recs[j], r1 = recs[j + 1], r2 = recs[j + 2], r3 = recs[j + 3];
        float f0 = bf2f(w1[(size_t)(r0.x >> 16) * NE_COL + (r0.x & 0xFFFF) * EMB + e]);
        float f1 = bf2f(w1[(size_t)(r1.x >> 16) * NE_COL + (r1.x & 0xFFFF) * EMB + e]);
        float f2 = bf2f(w1[(size_t)(r2.x >> 16) * NE_COL + (r2.x & 0xFFFF) * EMB + e]);
        float f3 = bf2f(w1[(size_t)(r3.x >> 16) * NE_COL + (r3.x & 0xFFFF) * EMB + e]);
        acc += __int_as_float(r0.y) * f0 + __int_as_float(r1.y) * f1 +
               __int_as_float(r2.y) * f2 + __int_as_float(r3.y) * f3;
    }
    for (; j < end; j++) {
        int2 rc = recs[j];
        acc += __int_as_float(rc.y) *
               bf2f(w1[(size_t)(rc.x >> 16) * NE_COL + (rc.x & 0xFFFF) * EMB + e]);
    }
    h[t] = fmaxf(acc + bias1[e], 0.f);
}

// ---- K6-alt (fallback if ws too small for w1): on-the-fly basis contraction -
__global__ void k_l1_gather_fly(const int* __restrict__ off, const int2* __restrict__ recs,
                                const float* __restrict__ comps1,
                                const float* __restrict__ bases1,
                                const float* __restrict__ bias1, float* __restrict__ h) {
    __shared__ float c1[R_TOT * NB];
    for (int q = threadIdx.x; q < R_TOT * NB; q += blockDim.x) c1[q] = comps1[q];
    __syncthreads();
    int t = blockIdx.x * blockDim.x + threadIdx.x;
    int s = t >> 4, e = t & 15;
    int beg = off[s], end = off[s + 1];
    float acc = 0.f;
    for (int j = beg; j < end; j++) {
        int2 rec = recs[j];
        int o = rec.x & 0xFFFF, r = rec.x >> 16;
        float v = __int_as_float(rec.y);
        const float* cr = &c1[r * NB];
        float w = 0.f;
#pragma unroll 8
        for (int b = 0; b < NB; b++) w += cr[b] * bases1[(size_t)b * NE_COL + o * EMB + e];
        acc += v * w;
    }
    h[t] = fmaxf(acc + bias1[e], 0.f);
}

// ---- K7: layer-2 gather, no shfl: all 16 lanes of an edge-group load the ----
// same 64B h[o,:] row (L1 broadcast) and dot it with their w2 column from LDS.
#define W2C 20
#define W2R (16 * W2C + 4)    // 324
__global__ void k_l2_gather(const int* __restrict__ off, const int2* __restrict__ recs,
                            const float* __restrict__ h, const float* __restrict__ w2t,
                            const float* __restrict__ bias2, float* __restrict__ out) {
    __shared__ __align__(16) float w2s[R_TOT * W2R];   // 53,136 B -> 3 blocks/CU @512
    for (int q = threadIdx.x; q < R_TOT * (EMB * NCLS); q += blockDim.x) {
        int r = q >> 8;
        int x = q & 255;
        int c = x >> 4, e = x & 15;
        w2s[r * W2R + c * W2C + e] = w2t[q];
    }
    __syncthreads();
    int t = blockIdx.x * blockDim.x + threadIdx.x;
    if (t >= NE_COL) return;
    int s = t >> 4, c = t & 15;
    int beg = off[s], end = off[s + 1];
    int cbase = c * W2C;
    float acc = 0.f;
    int j = beg;
    for (; j + 1 < end; j += 2) {
        int2 ra = recs[j], rb = recs[j + 1];
        const float4* ha = (const float4*)(h + (size_t)(ra.x & 0xFFFF) * EMB);
        const float4* hb = (const float4*)(h + (size_t)(rb.x & 0xFFFF) * EMB);
        float4 h0 = ha[0], h1 = ha[1], h2 = ha[2], h3 = ha[3];
        float4 g0 = hb[0], g1 = hb[1], g2 = hb[2], g3 = hb[3];
        const float4* wa = (const float4*)&w2s[(ra.x >> 16) * W2R + cbase];
        const float4* wb = (const float4*)&w2s[(rb.x >> 16) * W2R + cbase];
        float4 a0 = wa[0], a1 = wa[1], a2 = wa[2], a3 = wa[3];
        float4 b0 = wb[0], b1 = wb[1], b2 = wb[2], b3 = wb[3];
        float da, db;
        da  = h0.x * a0.x; da = fmaf(h0.y, a0.y, da); da = fmaf(h0.z, a0.z, da); da = fmaf(h0.w, a0.w, da);
        da = fmaf(h1.x, a1.x, da); da = fmaf(h1.y, a1.y, da); da = fmaf(h1.z, a1.z, da); da = fmaf(h1.w, a1.w, da);
        da = fmaf(h2.x, a2.x, da); da = fmaf(h2.y, a2.y, da); da = fmaf(h2.z, a2.z, da); da = fmaf(h2.w, a2.w, da);
        da = fmaf(h3.x, a3.x, da); da = fmaf(h3.y, a3.y, da); da = fmaf(h3.z, a3.z, da); da = fmaf(h3.w, a3.w, da);
        db  = g0.x * b0.x; db = fmaf(g0.y, b0.y, db); db = fmaf(g0.z, b0.z, db); db = fmaf(g0.w, b0.w, db);
        db = fmaf(g1.x, b1.x, db); db = fmaf(g1.y, b1.y, db); db = fmaf(g1.z, b1.z, db); db = fmaf(g1.w, b1.w, db);
        db = fmaf(g2.x, b2.x, db); db = fmaf(g2.y, b2.y, db); db = fmaf(g2.z, b2.z, db); db = fmaf(g2.w, b2.w, db);
        db = fmaf(g3.x, b3.x, db); db = fmaf(g3.y, b3.y, db); db = fmaf(g3.z, b3.z, db); db = fmaf(g3.w, b3.w, db);
        acc = fmaf(__int_as_float(ra.y), da, acc);
        acc = fmaf(__int_as_float(rb.y), db, acc);
    }
    for (; j < end; j++) {
        int2 ra = recs[j];
        const float4* ha = (const float4*)(h + (size_t)(ra.x & 0xFFFF) * EMB);
        float4 h0 = ha[0], h1 = ha[1], h2 = ha[2], h3 = ha[3];
        const float4* wa = (const float4*)&w2s[(ra.x >> 16) * W2R + cbase];
        float4 a0 = wa[0], a1 = wa[1], a2 = wa[2], a3 = wa[3];
        float da;
        da  = h0.x * a0.x; da = fmaf(h0.y, a0.y, da); da = fmaf(h0.z, a0.z, da); da = fmaf(h0.w, a0.w, da);
        da = fmaf(h1.x, a1.x, da); da = fmaf(h1.y, a1.y, da); da = fmaf(h1.z, a1.z, da); da = fmaf(h1.w, a1.w, da);
        da = fmaf(h2.x, a2.x, da); da = fmaf(h2.y, a2.y, da); da = fmaf(h2.z, a2.z, da); da = fmaf(h2.w, a2.w, da);
        da = fmaf(h3.x, a3.x, da); da = fmaf(h3.y, a3.y, da); da = fmaf(h3.z, a3.z, da); da = fmaf(h3.w, a3.w, da);
        acc = fmaf(__int_as_float(ra.y), da, acc);
    }
    out[s * NCLS + c] = acc + bias2[c];
}

static inline size_t align64(size_t x) { return (x + 63) & ~(size_t)63; }

extern "C" void kernel_launch(void* const* d_in, const int* in_sizes, int n_in,
                              void* d_out, int out_size, void* d_ws, size_t ws_size,
                              hipStream_t stream) {
    const int*   src    = (const int*)d_in[0];
    const int*   dst    = (const int*)d_in[1];
    const int*   rel    = (const int*)d_in[2];
    const float* comps1 = (const float*)d_in[3];
    const float* bases1 = (const float*)d_in[4];
    const float* comps2 = (const float*)d_in[5];
    const float* bases2 = (const float*)d_in[6];
    const float* bias1  = (const float*)d_in[7];
    const float* bias2  = (const float*)d_in[8];
    float* out = (float*)d_out;
    (void)in_sizes; (void)n_in; (void)out_size;

    char* ws = (char*)d_ws;
    size_t off_b = 0;
    // w1 (bf16, 65.6 MB) first; cnt2 (16.4MB) + rank (4.2MB) alias its head
    // (both dead before k_w1 writes w1).
    unsigned short* w1 = (unsigned short*)ws;
    int2*  cnt2 = (int2*)ws;
    int*   rank = (int*)(ws + align64((size_t)R_TOT * N_NODES * 8));
    off_b = align64((size_t)R_TOT * NE_COL * 2);              // 65.6 MB
    int*   deg  = (int*)(ws + off_b);  off_b = align64(off_b + (size_t)N_NODES * 4);
    int*   off  = (int*)(ws + off_b);  off_b = align64(off_b + (size_t)(N_NODES + 1) * 4);
    int*   bsum = (int*)(ws + off_b);  off_b = align64(off_b + (size_t)256 * 4);
    int2*  recs = (int2*)(ws + off_b); off_b = align64(off_b + (size_t)E_TOT * 8);
    float* h    = (float*)(ws + off_b); off_b = align64(off_b + (size_t)NE_COL * 4);
    float* w2t  = (float*)(ws + off_b); off_b = align64(off_b + (size_t)R_TOT * EMB * NCLS * 4);
    const bool materialize_w1 = (ws_size >= off_b);
    if (!materialize_w1) {
        off_b = 0;
        cnt2 = (int2*)(ws + off_b);  off_b = align64(off_b + (size_t)R_TOT * N_NODES * 8);
        rank = (int*)(ws + off_b);   off_b = align64(off_b + (size_t)E_TOT * 4);
        deg  = (int*)(ws + off_b);   off_b = align64(off_b + (size_t)N_NODES * 4);
        off  = (int*)(ws + off_b);   off_b = align64(off_b + (size_t)(N_NODES + 1) * 4);
        bsum = (int*)(ws + off_b);   off_b = align64(off_b + (size_t)256 * 4);
        recs = (int2*)(ws + off_b);  off_b = align64(off_b + (size_t)E_TOT * 8);
        h    = (float*)(ws + off_b); off_b = align64(off_b + (size_t)NE_COL * 4);
        w2t  = (float*)(ws + off_b); off_b = align64(off_b + (size_t)R_TOT * EMB * NCLS * 4);
    }

    // zero counts (.x of cnt2; .y overwritten by k_degA)
    hipMemsetAsync(cnt2, 0, (size_t)R_TOT * N_NODES * 8, stream);

    const int BLK = 256;
    const int g_edge = (E_TOT + BLK - 1) / BLK;           // 4102
    const int g_w1   = (NE_COL / 2 + BLK - 1) / BLK;      // 1563
    const int g_l1   = (N_NODES * 16) / BLK;              // 3125 (exact)
    const int g_l2   = (NE_COL + 511) / 512;              // 1563

    k_count<<<g_edge, BLK, 0, stream>>>(src, dst, rel, cnt2, rank);
    k_degA<<<NBLK_N, 256, 0, stream>>>(cnt2, deg, bsum);
    k_degB<<<1, 256, 0, stream>>>(bsum);
    k_degC<<<NBLK_N, 256, 0, stream>>>(deg, bsum, off);
    k_fill<<<g_edge, BLK, 0, stream>>>(src, dst, rel, cnt2, rank, off, recs);
    k_w2<<<R_TOT, EMB * NCLS, 0, stream>>>(comps2, bases2, w2t);

    if (materialize_w1) {
        k_w1<<<g_w1, BLK, 0, stream>>>(comps1, bases1, (unsigned*)w1);  // overwrites cnt2/rank (dead)
        k_l1_gather<<<g_l1, BLK, 0, stream>>>(off, recs, w1, bias1, h);
    } else {
        k_l1_gather_fly<<<g_l1, BLK, 0, stream>>>(off, recs, comps1, bases1, bias1, h);
    }

    k_l2_gather<<<g_l2, 512, 0, stream>>>(off, recs, h, w2t, bias2, out);
}